// Round 4
// baseline (12094.965 us; speedup 1.0000x reference)
//
#include <hip/hip_runtime.h>

// ---------------------------------------------------------------------------
// LSTM classifier, fp32 baseline (round 2: x/lengths are int32, not int64 —
// JAX x64-disabled demotes jnp.int64 to int32; harness delivers int32).
//   B=256, T=512, E=256, H=512, VOCAB=14.
// Strategy:
//   - table[v][2048] = emb[v] @ W_x(all 4 gates, packed) + bias  (input path)
//   - Wpack[k][4*j+g] = W_g[256+k][j]   (recurrent weights, gate-interleaved)
//   - rows counting-sorted by length DESC; step t processes rows [0, nact[t]).
//     A row's h stops being updated after its last step -> h IS last_hidden.
//   - h double-buffered (step t reads buf[t&1], writes buf[(t+1)&1]); c in place.
//   - 512 per-step kernel launches (graph nodes), t baked in at enqueue.
// ---------------------------------------------------------------------------

#define B_      256
#define T_      512
#define E_      256
#define H_      512
#define GC_     2048   // 4*H gate columns
#define VOCAB_  14

// ws layout (float slots)
#define WPACK_OFF 0
#define TBL_OFF   (512 * 2048)
#define H0_OFF    (TBL_OFF + VOCAB_ * GC_)
#define H1_OFF    (H0_OFF + B_ * H_)
#define C_OFF     (H1_OFF + B_ * H_)
#define XST_OFF   (C_OFF + B_ * H_)       // int tokens, [T][B]
#define PERM_OFF  (XST_OFF + T_ * B_)     // int
#define SLEN_OFF  (PERM_OFF + B_)         // int
#define NACT_OFF  (SLEN_OFF + B_)         // int, [T]

// ---------------------------------------------------------------------------
__global__ void zero_f(float* p, int n) {
    int i = blockIdx.x * blockDim.x + threadIdx.x;
    int stride = gridDim.x * blockDim.x;
    for (; i < n; i += stride) p[i] = 0.f;
}

// Wpack[k*2048 + (j<<2|g)] = W_g[(256+k)*512 + j]
__global__ void pack_w(const float* __restrict__ Wf, const float* __restrict__ Wi,
                       const float* __restrict__ Wc, const float* __restrict__ Wo,
                       float* __restrict__ Wpack) {
    int idx = blockIdx.x * 256 + threadIdx.x;
    if (idx >= 512 * 2048) return;
    int k = idx >> 11, cc = idx & 2047, j = cc >> 2, g = cc & 3;
    const float* W = (g == 0) ? Wf : (g == 1) ? Wi : (g == 2) ? Wc : Wo;
    Wpack[idx] = W[(E_ + k) * H_ + j];
}

// tbl[v*2048 + (j<<2|g)] = sum_e emb[v][e]*W_g[e][j] + b_g[j]
__global__ void build_table(const float* __restrict__ emb,
                            const float* __restrict__ Wf, const float* __restrict__ Wi,
                            const float* __restrict__ Wc, const float* __restrict__ Wo,
                            const float* __restrict__ bf, const float* __restrict__ bi,
                            const float* __restrict__ bc, const float* __restrict__ bo,
                            float* __restrict__ tbl) {
    int idx = blockIdx.x * 256 + threadIdx.x;
    if (idx >= VOCAB_ * GC_) return;
    int v = idx >> 11, cc = idx & 2047, j = cc >> 2, g = cc & 3;
    const float* W = (g == 0) ? Wf : (g == 1) ? Wi : (g == 2) ? Wc : Wo;
    const float* b = (g == 0) ? bf : (g == 1) ? bi : (g == 2) ? bc : bo;
    float s = b[j];
    const float* ev = emb + v * E_;
    for (int e = 0; e < E_; ++e) s += ev[e] * W[e * H_ + j];
    tbl[idx] = s;
}

// counting sort by length descending; nact[t] = #{len > t}
__global__ void sortlen(const int* __restrict__ lengths,
                        int* __restrict__ perm, int* __restrict__ slen,
                        int* __restrict__ nact) {
    __shared__ int cnt[513];
    __shared__ int off[513];
    int tid = threadIdx.x;  // 1024 threads
    if (tid < 513) cnt[tid] = 0;
    __syncthreads();
    if (tid < B_) atomicAdd(&cnt[lengths[tid]], 1);
    __syncthreads();
    if (tid <= 512) {
        int s = 0;
        for (int L = tid + 1; L <= 512; ++L) s += cnt[L];
        off[tid] = s;                 // scatter base for rows with len==tid
        if (tid < 512) nact[tid] = s; // #rows with len > tid
    }
    __syncthreads();
    if (tid < B_) {
        int L = lengths[tid];
        int p = atomicAdd(&off[L], 1);
        perm[p] = tid;
        slen[p] = L;
    }
}

// xsT[t*256 + r] = x[perm[r]][t]
__global__ void gatherx(const int* __restrict__ x, const int* __restrict__ perm,
                        int* __restrict__ xsT) {
    int t = blockIdx.x;
    int r = threadIdx.x;
    xsT[t * B_ + r] = x[perm[r] * T_ + t];
}

// ---------------------------------------------------------------------------
// One LSTM step: gates[r, c] = table[tok(r,t)][c] + sum_k hA[r][k]*Wpack[k][c]
// then activations + c/h update for rows r < nact[t].
// Tile: BM=32 rows x BN=32 gate cols (8 hidden units). 128 threads, 2x4 micro.
// Grid: (2048/32=64, 256/32=8).
// ---------------------------------------------------------------------------
#define BM 32
#define BN 32
#define BK 32

__global__ __launch_bounds__(128) void lstm_step(
    const float* __restrict__ Wpack, const float* __restrict__ tbl,
    const int* __restrict__ xsT, const float* __restrict__ hA,
    float* __restrict__ hB, float* __restrict__ cbuf,
    const int* __restrict__ nact, int t) {
    int n = nact[t];
    int r0 = blockIdx.y * BM;
    if (r0 >= n) return;
    int c0 = blockIdx.x * BN;

    __shared__ float hsT[BK][BM + 2];   // [k][m], +2 keeps float2 alignment
    __shared__ float wt[BK][BN];        // [k][c]

    int tid = threadIdx.x;
    int tn = tid & 7;    // col group: cols tn*4 .. tn*4+3 (one hidden unit)
    int tm = tid >> 3;   // row group: rows tm*2, tm*2+1   (tm in [0,16))

    float acc[2][4] = {{0.f, 0.f, 0.f, 0.f}, {0.f, 0.f, 0.f, 0.f}};

    for (int k0 = 0; k0 < H_; k0 += BK) {
        // stage h tile transposed: 32 rows x 32 k  (1024 elems, 8/thread)
#pragma unroll
        for (int e = 0; e < 8; ++e) {
            int idx = tid + e * 128;
            int k = idx & 31, m = idx >> 5;
            hsT[k][m] = hA[(r0 + m) * H_ + k0 + k];  // rows >= n harmless (write guarded)
        }
        // stage W tile: 32 k x 32 cols (1024 elems, 8/thread)
#pragma unroll
        for (int e = 0; e < 8; ++e) {
            int idx = tid + e * 128;
            int c = idx & 31, k = idx >> 5;
            wt[k][c] = Wpack[(k0 + k) * GC_ + c0 + c];
        }
        __syncthreads();
#pragma unroll
        for (int k = 0; k < BK; ++k) {
            float2 a = *(const float2*)&hsT[k][tm * 2];
            float4 b = *(const float4*)&wt[k][tn * 4];
            acc[0][0] += a.x * b.x; acc[0][1] += a.x * b.y;
            acc[0][2] += a.x * b.z; acc[0][3] += a.x * b.w;
            acc[1][0] += a.y * b.x; acc[1][1] += a.y * b.y;
            acc[1][2] += a.y * b.z; acc[1][3] += a.y * b.w;
        }
        __syncthreads();
    }

    int u = (c0 >> 2) + tn;  // hidden unit owned by this thread
#pragma unroll
    for (int mm = 0; mm < 2; ++mm) {
        int r = r0 + tm * 2 + mm;
        if (r < n) {
            int tok = xsT[t * B_ + r];
            float4 tb = *(const float4*)&tbl[tok * GC_ + c0 + tn * 4];
            float pf = acc[mm][0] + tb.x;
            float pi = acc[mm][1] + tb.y;
            float pc = acc[mm][2] + tb.z;
            float po = acc[mm][3] + tb.w;
            float f = 1.f / (1.f + expf(-pf));
            float i = 1.f / (1.f + expf(-pi));
            float ch = tanhf(pc);
            float o = 1.f / (1.f + expf(-po));
            float cn = f * cbuf[r * H_ + u] + i * ch;
            cbuf[r * H_ + u] = cn;
            hB[r * H_ + u] = o * tanhf(cn);
        }
    }
}

// out[perm[r]] = sigmoid(dot(h_final[r], fcW) + fcb)
__global__ void fc_out(const float* __restrict__ h0, const float* __restrict__ h1,
                       const float* __restrict__ fcW, const float* __restrict__ fcb,
                       const int* __restrict__ perm, const int* __restrict__ slen,
                       float* __restrict__ out) {
    int r = blockIdx.x;
    int lane = threadIdx.x;  // 64
    const float* h = (((slen[r] & 1) ? h1 : h0)) + r * H_;
    float s = 0.f;
    for (int j = lane; j < H_; j += 64) s += h[j] * fcW[j];
#pragma unroll
    for (int o = 32; o > 0; o >>= 1) s += __shfl_down(s, o);
    if (lane == 0) {
        float tot = s + fcb[0];
        out[perm[r]] = 1.f / (1.f + expf(-tot));
    }
}

// ---------------------------------------------------------------------------
extern "C" void kernel_launch(void* const* d_in, const int* in_sizes, int n_in,
                              void* d_out, int out_size, void* d_ws, size_t ws_size,
                              hipStream_t stream) {
    const int* x   = (const int*)d_in[0];
    const int* len = (const int*)d_in[1];
    const float* emb = (const float*)d_in[2];
    const float* Wf  = (const float*)d_in[3];
    const float* bf  = (const float*)d_in[4];
    const float* Wi  = (const float*)d_in[5];
    const float* bi  = (const float*)d_in[6];
    const float* Wc  = (const float*)d_in[7];
    const float* bc  = (const float*)d_in[8];
    const float* Wo  = (const float*)d_in[9];
    const float* bo  = (const float*)d_in[10];
    const float* fcW = (const float*)d_in[11];
    const float* fcb = (const float*)d_in[12];
    float* out = (float*)d_out;

    float* wsf   = (float*)d_ws;
    float* Wpack = wsf + WPACK_OFF;
    float* tbl   = wsf + TBL_OFF;
    float* h0    = wsf + H0_OFF;
    float* h1    = wsf + H1_OFF;
    float* cb    = wsf + C_OFF;
    int*   xsT   = (int*)(wsf + XST_OFF);
    int*   perm  = (int*)(wsf + PERM_OFF);
    int*   slen  = (int*)(wsf + SLEN_OFF);
    int*   nact  = (int*)(wsf + NACT_OFF);

    // init state (ws is re-poisoned before every timed call)
    zero_f<<<384, 256, 0, stream>>>(h0, 3 * B_ * H_);  // h0,h1,c contiguous
    pack_w<<<(512 * 2048 + 255) / 256, 256, 0, stream>>>(Wf, Wi, Wc, Wo, Wpack);
    build_table<<<(VOCAB_ * GC_ + 255) / 256, 256, 0, stream>>>(
        emb, Wf, Wi, Wc, Wo, bf, bi, bc, bo, tbl);
    sortlen<<<1, 1024, 0, stream>>>(len, perm, slen, nact);
    gatherx<<<T_, B_, 0, stream>>>(x, perm, xsT);

    for (int t = 0; t < T_; ++t) {
        const float* hA = (t & 1) ? h1 : h0;
        float*       hB = (t & 1) ? h0 : h1;
        lstm_step<<<dim3(GC_ / BN, B_ / BM), 128, 0, stream>>>(
            Wpack, tbl, xsT, hA, hB, cb, nact, t);
    }

    fc_out<<<B_, 64, 0, stream>>>(h0, h1, fcW, fcb, perm, slen, out);
}

// Round 11
// 9219.381 us; speedup vs baseline: 1.3119x; 1.3119x over previous
//
#include <hip/hip_runtime.h>

// ---------------------------------------------------------------------------
// LSTM classifier — persistent kernel, W-in-VGPR, flag-tree group barrier.
//   B=256, T=512, E=256, H=512, VOCAB=14.
// ROUND-10 FIX: ws layout. h (256x512 bf16) = 65536 float-slots, NOT 32768.
//   The old defines made h1 overlap FLG/SEN/XST -> garbage tokens -> OOB
//   tbl reads -> GPU memory fault -> SIGABRT (rounds 5 AND 9 explained).
// - input path folded into tbl[14][2048] (emb@Wx+b, gate-interleaved col=4u+g)
// - recurrent W held as bf16 MFMA B-fragments in REGISTERS (128 VGPR/wave)
// - grid 64 WGs = 8 row-groups (32 rows) x 8 unit-WGs (64 units, 512 thr);
//   group barrier = per-WG flag slots + sentinel, agent-scope atomics,
//   capped spins (failure -> wrong answer, not watchdog abort)
// - c-state in registers; h bf16 double-buffered in global
// - rows counting-sorted by length desc; group exits at its block max length
// ---------------------------------------------------------------------------

typedef __attribute__((ext_vector_type(8))) short short8;
typedef __attribute__((ext_vector_type(4))) float f32x4;

#define B_      256
#define T_      512
#define H_      512
#define GC_     2048
#define VOCAB_  14
#define NG_     8     // row groups
#define GSZ_    8     // WGs per group
#define ROWS_G  32    // rows per group
#define SPIN_CAP 100000

// ws layout (float slots)
#define TBL_OFF  0
#define H0_OFF   (VOCAB_ * GC_)            // 28672
#define H1_OFF   (H0_OFF + 65536)          // h bf16 256x512 = 131072 ushort = 65536 f-slots
#define FLG_OFF  (H1_OFF + 65536)          // 256 ints
#define SEN_OFF  (FLG_OFF + 256)           // 256 ints
#define XST_OFF  (SEN_OFF + 256)           // int tokens [T][B]
#define PERM_OFF (XST_OFF + T_ * B_)
#define SLEN_OFF (PERM_OFF + B_)

__device__ __forceinline__ ushort f2bf(float f) {
    uint u = __float_as_uint(f);
    return (ushort)((u + 0x7fffu + ((u >> 16) & 1u)) >> 16);
}
__device__ __forceinline__ float bf2f(ushort s) {
    return __uint_as_float(((uint)s) << 16);
}

__global__ void zero_f(float* p, int n) {
    int i = blockIdx.x * blockDim.x + threadIdx.x;
    int stride = gridDim.x * blockDim.x;
    for (; i < n; i += stride) p[i] = 0.f;
}

// tbl[v*2048 + (u<<2|g)] = sum_e emb[v][e]*W_g[e][u] + b_g[u]
__global__ void build_table(const float* __restrict__ emb,
                            const float* __restrict__ Wf, const float* __restrict__ Wi,
                            const float* __restrict__ Wc, const float* __restrict__ Wo,
                            const float* __restrict__ bf, const float* __restrict__ bi,
                            const float* __restrict__ bc, const float* __restrict__ bo,
                            float* __restrict__ tbl) {
    int idx = blockIdx.x * 256 + threadIdx.x;
    if (idx >= VOCAB_ * GC_) return;
    int v = idx >> 11, cc = idx & 2047, u = cc >> 2, g = cc & 3;
    const float* W = (g == 0) ? Wf : (g == 1) ? Wi : (g == 2) ? Wc : Wo;
    const float* b = (g == 0) ? bf : (g == 1) ? bi : (g == 2) ? bc : bo;
    float s = b[u];
    const float* ev = emb + v * 256;
    for (int e = 0; e < 256; ++e) s += ev[e] * W[e * H_ + u];
    tbl[idx] = s;
}

// counting sort by length descending
__global__ void sortlen(const int* __restrict__ lengths,
                        int* __restrict__ perm, int* __restrict__ slen) {
    __shared__ int cnt[513];
    __shared__ int off[513];
    int tid = threadIdx.x;  // 1024
    if (tid < 513) cnt[tid] = 0;
    __syncthreads();
    if (tid < B_) atomicAdd(&cnt[lengths[tid]], 1);
    __syncthreads();
    if (tid <= 512) {
        int s = 0;
        for (int L = tid + 1; L <= 512; ++L) s += cnt[L];
        off[tid] = s;
    }
    __syncthreads();
    if (tid < B_) {
        int L = lengths[tid];
        int p = atomicAdd(&off[L], 1);
        perm[p] = tid;
        slen[p] = L;
    }
}

__global__ void gatherx(const int* __restrict__ x, const int* __restrict__ perm,
                        int* __restrict__ xsT) {
    int t = blockIdx.x;
    int r = threadIdx.x;
    xsT[t * B_ + r] = x[perm[r] * T_ + t];
}

// ---------------------------------------------------------------------------
// Persistent kernel. 64 WGs x 512 threads (8 waves).
// WG (g = bid&7, jb = bid>>3): rows g*32..+32, units jb*64..+64.
// Wave w: units jb*64 + w*8 ..+8 (32 gate cols = 2 N-tiles of 16).
// B-fragments for mfma_f32_16x16x32_bf16 live in VGPRs (bfr[2][16], 128 regs).
// ---------------------------------------------------------------------------
__global__ __launch_bounds__(512, 1) void lstm_persist(
    const float* __restrict__ Wf, const float* __restrict__ Wi,
    const float* __restrict__ Wc, const float* __restrict__ Wo,
    const float* __restrict__ tbl, const int* __restrict__ xsT,
    const int* __restrict__ slen, ushort* __restrict__ h0,
    ushort* __restrict__ h1, int* __restrict__ flg, int* __restrict__ sen) {
    const int bid = blockIdx.x;
    const int g   = bid & 7;      // row-group
    const int jb  = bid >> 3;     // unit-block (64 units)
    const int tid = threadIdx.x;
    const int w    = tid >> 6;    // wave 0..7
    const int lane = tid & 63;
    const int grow0 = g * ROWS_G;

    __shared__ float xch[8 * 32 * 36];   // per-wave [32 gc][36] bounce, 36 KB

    // ---- preload recurrent W as B-fragments in registers ----
    // B-layout (16x16x32): lane l holds col n=l&15, k = (l>>4)*8 + jj.
    // col n -> unit (n>>2) of the N-tile, gate = n&3; value = W_g[256+k][unit].
    short8 bfr[2][16];
    {
        const int n = lane & 15, q = lane >> 4, gg = n & 3;
        const float* Wg = (gg == 0) ? Wf : (gg == 1) ? Wi : (gg == 2) ? Wc : Wo;
#pragma unroll
        for (int nt = 0; nt < 2; ++nt) {
            int ucol = jb * 64 + w * 8 + nt * 4 + (n >> 2);
#pragma unroll
            for (int kt = 0; kt < 16; ++kt) {
                short8 bb;
#pragma unroll
                for (int jj = 0; jj < 8; ++jj) {
                    ((ushort*)&bb)[jj] = f2bf(Wg[(256 + kt * 32 + q * 8 + jj) * H_ + ucol]);
                }
                bfr[nt][kt] = bb;
            }
        }
    }

    // ---- per-lane state ----
    const int tmax = slen[grow0];              // group max (sorted desc)
    const int u_e = lane & 7, r4 = lane >> 3;  // epilogue: unit, row residue
    const int ug = jb * 64 + w * 8 + u_e;      // global unit
    float c[4];
    int lenr[4];
#pragma unroll
    for (int rr = 0; rr < 4; ++rr) {
        c[rr] = 0.f;
        lenr[rr] = slen[grow0 + rr * 8 + r4];
    }
    float* xw = &xch[w * 1152];
    int* myflg = &flg[g * GSZ_];
    int* mysen = &sen[g];
    const int rA = grow0 + (lane & 15);        // A-frag row (mt=0)
    const int ko = (lane >> 4) * 8;            // A-frag k offset

    for (int t = 0; t < tmax; ++t) {
        const ushort* hc = (t & 1) ? h1 : h0;
        ushort* hn = (t & 1) ? h0 : h1;

        // ---- gates = h @ Wpack : 2 M-tiles x 2 N-tiles x 16 K-tiles ----
        f32x4 a00 = {0.f,0.f,0.f,0.f}, a01 = {0.f,0.f,0.f,0.f};
        f32x4 a10 = {0.f,0.f,0.f,0.f}, a11 = {0.f,0.f,0.f,0.f};
#pragma unroll
        for (int kt = 0; kt < 16; ++kt) {
            short8 av0 = *(const short8*)&hc[rA * H_ + kt * 32 + ko];
            short8 av1 = *(const short8*)&hc[(rA + 16) * H_ + kt * 32 + ko];
            a00 = __builtin_amdgcn_mfma_f32_16x16x32_bf16(av0, bfr[0][kt], a00, 0, 0, 0);
            a01 = __builtin_amdgcn_mfma_f32_16x16x32_bf16(av0, bfr[1][kt], a01, 0, 0, 0);
            a10 = __builtin_amdgcn_mfma_f32_16x16x32_bf16(av1, bfr[0][kt], a10, 0, 0, 0);
            a11 = __builtin_amdgcn_mfma_f32_16x16x32_bf16(av1, bfr[1][kt], a11, 0, 0, 0);
        }

        // ---- bounce acc -> xw[gc_loc][row] (wave-private, no barrier) ----
        {
            int n = lane & 15, qq = (lane >> 4) * 4;
            *(f32x4*)&xw[n * 36 + qq]             = a00;
            *(f32x4*)&xw[(16 + n) * 36 + qq]      = a01;
            *(f32x4*)&xw[n * 36 + 16 + qq]        = a10;
            *(f32x4*)&xw[(16 + n) * 36 + 16 + qq] = a11;
        }

        // ---- activations + state update: 4 (row,unit) pairs per lane ----
#pragma unroll
        for (int rr = 0; rr < 4; ++rr) {
            int row = rr * 8 + r4;
            int tok = xsT[t * B_ + grow0 + row];
            f32x4 tb = *(const f32x4*)&tbl[tok * GC_ + ug * 4];
            int gl = (u_e >> 2) * 16 + (u_e & 3) * 4;
            float pf = xw[(gl + 0) * 36 + row] + tb.x;
            float pi = xw[(gl + 1) * 36 + row] + tb.y;
            float pc = xw[(gl + 2) * 36 + row] + tb.z;
            float po = xw[(gl + 3) * 36 + row] + tb.w;
            float fg = 1.f / (1.f + __expf(-pf));
            float ig = 1.f / (1.f + __expf(-pi));
            float cg = 2.f / (1.f + __expf(-2.f * pc)) - 1.f;
            float og = 1.f / (1.f + __expf(-po));
            float cn = fg * c[rr] + ig * cg;
            float hh = og * (2.f / (1.f + __expf(-2.f * cn)) - 1.f);
            if (t < lenr[rr]) {  // freeze row at its length; h(len) survives
                c[rr] = cn;
                hn[(grow0 + row) * H_ + ug] = f2bf(hh);
            }
        }

        // ---- group barrier: per-WG flag slots + sentinel (capped spins) ----
        __syncthreads();                 // all waves done; vmcnt drained
        if (tid == 0) {
            __threadfence();             // release: h stores device-visible
            __hip_atomic_store(&myflg[jb], t + 1, __ATOMIC_RELAXED,
                               __HIP_MEMORY_SCOPE_AGENT);
        }
        if (jb == 0) {
            if (tid < GSZ_) {            // wave-0 lanes poll 8 slots in parallel
                int sp = 0;
                while (__hip_atomic_load(&myflg[tid], __ATOMIC_RELAXED,
                                         __HIP_MEMORY_SCOPE_AGENT) <= t) {
                    __builtin_amdgcn_s_sleep(1);
                    if (++sp > SPIN_CAP) break;
                }
            }
            if (tid == 0) {              // after reconvergence of the pollers
                __threadfence();         // acquire flags -> carries h chain
                __hip_atomic_store(mysen, t + 1, __ATOMIC_RELAXED,
                                   __HIP_MEMORY_SCOPE_AGENT);
            }
        } else if (tid == 0) {
            int sp = 0;
            while (__hip_atomic_load(mysen, __ATOMIC_RELAXED,
                                     __HIP_MEMORY_SCOPE_AGENT) <= t) {
                __builtin_amdgcn_s_sleep(1);
                if (++sp > SPIN_CAP) break;
            }
        }
        __syncthreads();
        __threadfence();                 // acquire: fresh h visible to loads
    }
}

// out[perm[r]] = sigmoid(dot(h_final[r], fcW) + fcb); h_final in buf[len&1]
__global__ void fc_out(const ushort* __restrict__ h0, const ushort* __restrict__ h1,
                       const float* __restrict__ fcW, const float* __restrict__ fcb,
                       const int* __restrict__ perm, const int* __restrict__ slen,
                       float* __restrict__ out) {
    int r = blockIdx.x;
    int lane = threadIdx.x;  // 64
    const ushort* h = (((slen[r] & 1) ? h1 : h0)) + r * H_;
    float s = 0.f;
    for (int j = lane; j < H_; j += 64) s += bf2f(h[j]) * fcW[j];
#pragma unroll
    for (int o = 32; o > 0; o >>= 1) s += __shfl_down(s, o);
    if (lane == 0) {
        out[perm[r]] = 1.f / (1.f + expf(-(s + fcb[0])));
    }
}

// ---------------------------------------------------------------------------
extern "C" void kernel_launch(void* const* d_in, const int* in_sizes, int n_in,
                              void* d_out, int out_size, void* d_ws, size_t ws_size,
                              hipStream_t stream) {
    const int* x   = (const int*)d_in[0];
    const int* len = (const int*)d_in[1];
    const float* emb = (const float*)d_in[2];
    const float* Wf  = (const float*)d_in[3];
    const float* bfp = (const float*)d_in[4];
    const float* Wi  = (const float*)d_in[5];
    const float* bip = (const float*)d_in[6];
    const float* Wc  = (const float*)d_in[7];
    const float* bcp = (const float*)d_in[8];
    const float* Wo  = (const float*)d_in[9];
    const float* bop = (const float*)d_in[10];
    const float* fcW = (const float*)d_in[11];
    const float* fcb = (const float*)d_in[12];
    float* out = (float*)d_out;

    float* wsf = (float*)d_ws;
    float*  tbl  = wsf + TBL_OFF;
    ushort* h0   = (ushort*)(wsf + H0_OFF);
    ushort* h1   = (ushort*)(wsf + H1_OFF);
    int*    flg  = (int*)(wsf + FLG_OFF);
    int*    sen  = (int*)(wsf + SEN_OFF);
    int*    xsT  = (int*)(wsf + XST_OFF);
    int*    perm = (int*)(wsf + PERM_OFF);
    int*    slen = (int*)(wsf + SLEN_OFF);

    // zero h0,h1,flg,sen (contiguous; ws re-poisoned before every call)
    zero_f<<<512, 256, 0, stream>>>(wsf + H0_OFF, 2 * 65536 + 512);
    build_table<<<(VOCAB_ * GC_ + 255) / 256, 256, 0, stream>>>(
        emb, Wf, Wi, Wc, Wo, bfp, bip, bcp, bop, tbl);
    sortlen<<<1, 1024, 0, stream>>>(len, perm, slen);
    gatherx<<<T_, B_, 0, stream>>>(x, perm, xsT);

    lstm_persist<<<NG_ * GSZ_, 512, 0, stream>>>(
        Wf, Wi, Wc, Wo, tbl, xsT, slen, h0, h1, flg, sen);

    fc_out<<<B_, 64, 0, stream>>>(h0, h1, fcW, fcb, perm, slen, out);
}